// Round 7
// baseline (232.818 us; speedup 1.0000x reference)
//
#include <hip/hip_runtime.h>
#include <math.h>
#include <float.h>

#define B   256
#define D   256
#define D1  1024
#define D2  512
#define D3  256
#define NDIST (D1 + D2 + D3)   // 1792
#define CQ  2.0f               // qV2 static scale multiplier (step = sa[d]*CQ)

typedef __attribute__((ext_vector_type(8))) short short8;
typedef __attribute__((ext_vector_type(4))) float f32x4;
typedef __attribute__((ext_vector_type(4))) int   i32x4;

__device__ __forceinline__ float waveReduceSum(float v) {
    #pragma unroll
    for (int off = 32; off > 0; off >>= 1)
        v += __shfl_down(v, off, 64);
    return v;
}
__device__ __forceinline__ float waveReduceMax(float v) {
    #pragma unroll
    for (int off = 32; off > 0; off >>= 1)
        v = fmaxf(v, __shfl_down(v, off, 64));
    return v;
}

__device__ __forceinline__ unsigned short f2bf(float f) {
    unsigned int u = __float_as_uint(f);
    u = (u + 0x7FFFu + ((u >> 16) & 1u)) >> 16;   // RNE
    return (unsigned short)u;
}
__device__ __forceinline__ void gld16(const void* g, void* l) {
    __builtin_amdgcn_global_load_lds(
        (const __attribute__((address_space(1))) unsigned int*)g,
        (__attribute__((address_space(3))) unsigned int*)l, 16, 0, 0);
}

// ---- mega prep: zeros, bf16 splits, i8 quants, rn1 -------------------------
__global__ __launch_bounds__(256) void k_prep(
    const float* __restrict__ x,  const float* __restrict__ W1,
    const float* __restrict__ W2, const float* __restrict__ W3,
    float* __restrict__ norms,                 // norm2||norm3, 196608 floats
    float* __restrict__ outp,
    unsigned short* __restrict__ xhi,  unsigned short* __restrict__ W1hi,
    unsigned short* __restrict__ W2hi, unsigned short* __restrict__ W3hi,
    signed char* __restrict__ W1Ti8, float* __restrict__ saq,
    signed char* __restrict__ W2i8,  float* __restrict__ sbq,
    signed char* __restrict__ W3i8,  float* __restrict__ s3q,
    float* __restrict__ rn1) {
    int blk = blockIdx.x;
    int t = threadIdx.x;
    if (blk < 768) {                                   // zero norms (+ out)
        if (blk == 0 && t == 0) outp[0] = 0.f;
        norms[blk * 256 + t] = 0.f;
        return;
    }
    if (blk < 1728) {                                  // bf16 hi split
        int i4 = ((blk - 768) * 256 + t) * 4;
        const float* src; unsigned short* hi; int off;
        if (i4 < 65536)       { src = x;  hi = xhi;  off = i4; }
        else if (i4 < 327680) { src = W1; hi = W1hi; off = i4 - 65536; }
        else if (i4 < 851968) { src = W2; hi = W2hi; off = i4 - 327680; }
        else                  { src = W3; hi = W3hi; off = i4 - 851968; }
        float4 v = *(const float4*)(src + off);
        ushort4 h;
        h.x = f2bf(v.x); h.y = f2bf(v.y); h.z = f2bf(v.z); h.w = f2bf(v.w);
        *(ushort4*)(hi + off) = h;
        return;
    }
    if (blk < 1736) {                                  // W1 col quant (coalesced)
        __shared__ float smax[8][32];
        __shared__ signed char ctile[32][36];
        int d0 = (blk - 1728) * 32;
        int ty = t >> 5, tx = t & 31;
        float m = 0.f;
        for (int i = ty; i < D1; i += 8)
            m = fmaxf(m, fabsf(W1[(size_t)i * D + d0 + tx]));
        smax[ty][tx] = m;
        __syncthreads();
        if (ty == 0) {
            #pragma unroll
            for (int r = 1; r < 8; r++) m = fmaxf(m, smax[r][tx]);
            m = fmaxf(m, 1e-20f);
            saq[d0 + tx] = m / 127.f;
            smax[0][tx] = 127.f / m;
        }
        __syncthreads();
        float inv = smax[0][tx];
        for (int i0 = 0; i0 < D1; i0 += 32) {
            #pragma unroll
            for (int jj = 0; jj < 4; jj++) {
                int il = ty * 4 + jj;
                float v = W1[(size_t)(i0 + il) * D + d0 + tx];
                ctile[tx][il] = (signed char)__float2int_rn(v * inv);
            }
            __syncthreads();
            int td = t >> 3, tc = t & 7;
            *(int*)&W1Ti8[(size_t)(d0 + td) * D1 + i0 + tc * 4] =
                *(const int*)&ctile[td][tc * 4];
            __syncthreads();
        }
        return;
    }
    if (blk < 1864) {                                  // W2 row quant
        int o = (blk - 1736) * 4 + (t >> 6);
        int l = t & 63;
        const float* row = W2 + (size_t)o * D1;
        float m = 0.f;
        for (int tt = l; tt < D1; tt += 64) m = fmaxf(m, fabsf(row[tt]));
        m = waveReduceMax(m);
        m = __shfl(m, 0, 64);
        m = fmaxf(m, 1e-20f);
        if (l == 0) sbq[o] = m / 127.f;
        float inv = 127.f / m;
        for (int tt = l; tt < D1; tt += 64)
            W2i8[(size_t)o * D1 + tt] = (signed char)__float2int_rn(row[tt] * inv);
        return;
    }
    if (blk < 1928) {                                  // W3 row quant
        int p = (blk - 1864) * 4 + (t >> 6);
        int l = t & 63;
        const float* row = W3 + (size_t)p * D2;
        float m = 0.f;
        for (int tt = l; tt < D2; tt += 64) m = fmaxf(m, fabsf(row[tt]));
        m = waveReduceMax(m);
        m = __shfl(m, 0, 64);
        m = fmaxf(m, 1e-20f);
        if (l == 0) s3q[p] = m / 127.f;
        float inv = 127.f / m;
        for (int tt = l; tt < D2; tt += 64)
            W3i8[(size_t)p * D2 + tt] = (signed char)__float2int_rn(row[tt] * inv);
        return;
    }
    {                                                  // rn1 (W1 row norms)
        int gw = (blk - 1928) * 4 + (t >> 6);
        int lane = t & 63;
        const float* row = W1 + (size_t)gw * D;
        float s = 0.f;
        for (int tt = lane; tt < D; tt += 64) { float v = row[tt]; s += v * v; }
        s = waveReduceSum(s);
        if (lane == 0) rn1[gw] = sqrtf(s);
    }
}

// ---- layer GEMM core: 64x64 tile, split-K x4 (one K-quarter per wave), -----
// direct global bf16 frag loads (no LDS staging), LDS combine into lbuf[64*65].
template <int KD>
__device__ __forceinline__ void layer_gemm(
    const unsigned short* __restrict__ Ahi, const unsigned short* __restrict__ Bhi,
    int m0, int n0, float* lbuf) {
    int t = threadIdx.x;
    int l = t & 63, w = t >> 6;
    int quad = l >> 4, l16 = l & 15;
    const int KQ = KD / 4;
    f32x4 acc[4][4];
    #pragma unroll
    for (int i = 0; i < 4; i++)
        #pragma unroll
        for (int j = 0; j < 4; j++) acc[i][j] = (f32x4)0.f;
    for (int kk = 0; kk < KQ; kk += 32) {
        short8 a[4], bfr[4];
        #pragma unroll
        for (int mt = 0; mt < 4; mt++)
            a[mt] = *(const short8*)(Ahi + (size_t)(m0 + mt * 16 + l16) * KD +
                                     w * KQ + kk + quad * 8);
        #pragma unroll
        for (int nt = 0; nt < 4; nt++)
            bfr[nt] = *(const short8*)(Bhi + (size_t)(n0 + nt * 16 + l16) * KD +
                                       w * KQ + kk + quad * 8);
        #pragma unroll
        for (int mt = 0; mt < 4; mt++)
            #pragma unroll
            for (int nt = 0; nt < 4; nt++)
                acc[mt][nt] = __builtin_amdgcn_mfma_f32_16x16x32_bf16(
                    a[mt], bfr[nt], acc[mt][nt], 0, 0, 0);
    }
    // sequential wave combine into lbuf
    for (int pass = 0; pass < 4; pass++) {
        if (w == pass) {
            #pragma unroll
            for (int mt = 0; mt < 4; mt++)
                #pragma unroll
                for (int nt = 0; nt < 4; nt++)
                    #pragma unroll
                    for (int r = 0; r < 4; r++) {
                        int idx = (mt * 16 + quad * 4 + r) * 65 + nt * 16 + l16;
                        if (pass == 0) lbuf[idx] = acc[mt][nt][r];
                        else           lbuf[idx] += acc[mt][nt][r];
                    }
        }
        __syncthreads();
    }
}

// ---- layer 1: z1 -> dist1, m1q, h1hi ---------------------------------------
__global__ __launch_bounds__(256) void k_l1(
    const unsigned short* __restrict__ xhi, const unsigned short* __restrict__ W1hi,
    const float* __restrict__ b1, const float* __restrict__ rn1,
    float* __restrict__ dists, unsigned char* __restrict__ m1q,
    unsigned short* __restrict__ h1hi) {
    __shared__ float lbuf[64 * 65];
    int m0 = blockIdx.x * 64, n0 = blockIdx.y * 64;
    layer_gemm<D>(xhi, W1hi, m0, n0, lbuf);
    int t = threadIdx.x;
    int nl = t & 63, n = n0 + nl;
    float bv = b1[n], rv = rn1[n];
    int mg = (t >> 6) * 16;
    #pragma unroll
    for (int j = 0; j < 16; j++) {
        int ml = mg + j;
        float z = lbuf[ml * 65 + nl] + bv;
        size_t idx = (size_t)(m0 + ml) * D1 + n;
        dists[idx] = fabsf(z) / rv;
        m1q[idx] = (z > 0.f) ? 0xFFu : 0u;
        h1hi[idx] = f2bf(z > 0.f ? z : 0.f);
    }
}

// ---- layer 2: z2, m2q, h2hi ------------------------------------------------
__global__ __launch_bounds__(256) void k_l2(
    const unsigned short* __restrict__ h1hi, const unsigned short* __restrict__ W2hi,
    const float* __restrict__ b2, float* __restrict__ z2,
    unsigned char* __restrict__ m2q, unsigned short* __restrict__ h2hi) {
    __shared__ float lbuf[64 * 65];
    int m0 = blockIdx.x * 64, n0 = blockIdx.y * 64;
    layer_gemm<D1>(h1hi, W2hi, m0, n0, lbuf);
    int t = threadIdx.x;
    int nl = t & 63, n = n0 + nl;
    float bv = b2[n];
    int mg = (t >> 6) * 16;
    #pragma unroll
    for (int j = 0; j < 16; j++) {
        int ml = mg + j;
        float z = lbuf[ml * 65 + nl] + bv;
        size_t idx = (size_t)(m0 + ml) * D2 + n;
        z2[idx] = z;
        m2q[idx] = (z > 0.f) ? 0xFFu : 0u;
        h2hi[idx] = f2bf(z > 0.f ? z : 0.f);
    }
}

// ---- layer 3: z3 -----------------------------------------------------------
__global__ __launch_bounds__(256) void k_l3(
    const unsigned short* __restrict__ h2hi, const unsigned short* __restrict__ W3hi,
    const float* __restrict__ b3, float* __restrict__ z3) {
    __shared__ float lbuf[64 * 65];
    int m0 = blockIdx.x * 64, n0 = blockIdx.y * 64;
    layer_gemm<D2>(h2hi, W3hi, m0, n0, lbuf);
    int t = threadIdx.x;
    int nl = t & 63, n = n0 + nl;
    float bv = b3[n];
    int mg = (t >> 6) * 16;
    #pragma unroll
    for (int j = 0; j < 16; j++) {
        int ml = mg + j;
        z3[(size_t)(m0 + ml) * D3 + n] = lbuf[ml * 65 + nl] + bv;
    }
}

// ---- GEMM1 (i8, BK=128): C[o][d] = sum_i W2[o][i] * (m1 & W1T)[d][i] -------
__global__ __launch_bounds__(256) void k_gemm1(
    const signed char* __restrict__ W2i8,    // [512][1024]  A rows (o)
    const signed char* __restrict__ W1Ti8,   // [256][1024]  B rows (d)
    const unsigned char* __restrict__ m1q,   // [B][1024]
    const float* __restrict__ saq,           // [256]
    const float* __restrict__ sbq,           // [512]
    signed char* __restrict__ qV2,           // [CH][256][512] (d-major)
    float* __restrict__ norm2,               // [B][512]
    int b0) {
    __shared__ __align__(16) signed char As[16384];   // 128 rows x 128B
    __shared__ __align__(16) signed char Bs[16384];
    int m0 = blockIdx.x * 128;        // o
    int n0 = blockIdx.y * 128;        // d
    int bc = blockIdx.z;
    int b = b0 + bc;
    int tid = threadIdx.x;
    int l = tid & 63, w = tid >> 6;
    int quad = l >> 4, l16 = l & 15;
    int wm = (w >> 1) * 64, wn = (w & 1) * 64;
    const unsigned char* mrow = m1q + (size_t)b * D1;

    // staging: round r covers rows r*32 + w*8 + (l>>3); slot (l&7) holds chunk c
    const signed char* pa[4];
    const signed char* pb[4];
    int lrow = l >> 3, ls = l & 7;
    #pragma unroll
    for (int r = 0; r < 4; r++) {
        int row = r * 32 + w * 8 + lrow;
        int c = (ls + (row & 7)) & 7;
        pa[r] = W2i8 + (size_t)(m0 + row) * D1 + c * 16;
        pb[r] = W1Ti8 + (size_t)(n0 + row) * D1 + c * 16;
    }
    int aoff[4][2], boff[4][2];
    #pragma unroll
    for (int mt = 0; mt < 4; mt++) {
        int tr = wm + mt * 16 + l16;
        #pragma unroll
        for (int ks = 0; ks < 2; ks++)
            aoff[mt][ks] = tr * 128 + (((ks * 4 + quad) - (tr & 7)) & 7) * 16;
    }
    #pragma unroll
    for (int nt = 0; nt < 4; nt++) {
        int tr = wn + nt * 16 + l16;
        #pragma unroll
        for (int ks = 0; ks < 2; ks++)
            boff[nt][ks] = tr * 128 + (((ks * 4 + quad) - (tr & 7)) & 7) * 16;
    }

    i32x4 acc[4][4];
    #pragma unroll
    for (int i = 0; i < 4; i++)
        #pragma unroll
        for (int j = 0; j < 4; j++) acc[i][j] = (i32x4)0;

    for (int kk = 0; kk < D1; kk += 128) {
        #pragma unroll
        for (int r = 0; r < 4; r++) {
            gld16(pa[r] + kk, As + r * 4096 + w * 1024);
            gld16(pb[r] + kk, Bs + r * 4096 + w * 1024);
        }
        i32x4 mv0 = *(const i32x4*)(mrow + kk + quad * 16);
        i32x4 mv1 = *(const i32x4*)(mrow + kk + 64 + quad * 16);
        __syncthreads();
        #pragma unroll
        for (int ks = 0; ks < 2; ks++) {
            i32x4 mv = ks ? mv1 : mv0;
            i32x4 a[4], bq[4];
            #pragma unroll
            for (int mt = 0; mt < 4; mt++)
                a[mt] = *(const i32x4*)(As + aoff[mt][ks]);
            #pragma unroll
            for (int nt = 0; nt < 4; nt++)
                bq[nt] = (*(const i32x4*)(Bs + boff[nt][ks])) & mv;
            #pragma unroll
            for (int mt = 0; mt < 4; mt++)
                #pragma unroll
                for (int nt = 0; nt < 4; nt++)
                    acc[mt][nt] = __builtin_amdgcn_mfma_i32_16x16x64_i8(
                        a[mt], bq[nt], acc[mt][nt], 0, 0, 0);
        }
        __syncthreads();
    }

    // scales: o per (mt,r) rows; d per (nt) cols
    float sbd[4][4];
    #pragma unroll
    for (int mt = 0; mt < 4; mt++)
        #pragma unroll
        for (int r = 0; r < 4; r++)
            sbd[mt][r] = sbq[m0 + wm + mt * 16 + quad * 4 + r] * (1.0f / CQ);
    float saCQ[4];
    #pragma unroll
    for (int nt = 0; nt < 4; nt++)
        saCQ[nt] = saq[n0 + wn + nt * 16 + l16] * CQ;

    // norm2[o] += sum_d V2^2
    #pragma unroll
    for (int mt = 0; mt < 4; mt++)
        #pragma unroll
        for (int r = 0; r < 4; r++) {
            float s = 0.f;
            #pragma unroll
            for (int nt = 0; nt < 4; nt++) {
                float v = (float)acc[mt][nt][r] * sbd[mt][r] * saCQ[nt];
                s += v * v;
            }
            s += __shfl_down(s, 8, 64);
            s += __shfl_down(s, 4, 64);
            s += __shfl_down(s, 2, 64);
            s += __shfl_down(s, 1, 64);
            if (l16 == 0)
                atomicAdd(&norm2[(size_t)b * D2 + m0 + wm + mt * 16 + quad * 4 + r], s);
        }

    // qV2[d][o]: pack 4 consecutive-o int8 per dword
    signed char* qb = qV2 + (size_t)bc * (D * D2);
    #pragma unroll
    for (int nt = 0; nt < 4; nt++) {
        int d = n0 + wn + nt * 16 + l16;
        #pragma unroll
        for (int mt = 0; mt < 4; mt++) {
            int obase = m0 + wm + mt * 16 + quad * 4;
            unsigned int pk = 0;
            #pragma unroll
            for (int r = 0; r < 4; r++) {
                int qi = __float2int_rn((float)acc[mt][nt][r] * sbd[mt][r]);
                qi = max(-127, min(127, qi));
                pk |= ((unsigned int)(qi & 255)) << (8 * r);
            }
            *(unsigned int*)(qb + (size_t)d * D2 + obase) = pk;
        }
    }
}

// ---- GEMM2 (i8, BK=128): norm3[b][p] += s3[p]^2*sum_d (saCQ[d]*S3[p][d])^2 -
__global__ __launch_bounds__(256) void k_gemm2(
    const signed char* __restrict__ W3i8,    // [256][512]
    const signed char* __restrict__ qV2,     // [CH][256][512]
    const unsigned char* __restrict__ m2q,   // [B][512]
    const float* __restrict__ saq,           // [256]
    const float* __restrict__ s3q,           // [256]
    float* __restrict__ norm3,               // [B][256]
    int b0) {
    __shared__ __align__(16) signed char As[16384];
    __shared__ __align__(16) signed char Bs[16384];
    int m0 = blockIdx.x * 128;        // p
    int n0 = blockIdx.y * 128;        // d
    int bc = blockIdx.z;
    int b = b0 + bc;
    int tid = threadIdx.x;
    int l = tid & 63, w = tid >> 6;
    int quad = l >> 4, l16 = l & 15;
    int wm = (w >> 1) * 64, wn = (w & 1) * 64;
    const unsigned char* mrow = m2q + (size_t)b * D2;
    const signed char* Bsrc = qV2 + (size_t)bc * (D * D2);

    const signed char* pa[4];
    const signed char* pb[4];
    int lrow = l >> 3, ls = l & 7;
    #pragma unroll
    for (int r = 0; r < 4; r++) {
        int row = r * 32 + w * 8 + lrow;
        int c = (ls + (row & 7)) & 7;
        pa[r] = W3i8 + (size_t)(m0 + row) * D2 + c * 16;
        pb[r] = Bsrc + (size_t)(n0 + row) * D2 + c * 16;
    }
    int aoff[4][2], boff[4][2];
    #pragma unroll
    for (int mt = 0; mt < 4; mt++) {
        int tr = wm + mt * 16 + l16;
        #pragma unroll
        for (int ks = 0; ks < 2; ks++)
            aoff[mt][ks] = tr * 128 + (((ks * 4 + quad) - (tr & 7)) & 7) * 16;
    }
    #pragma unroll
    for (int nt = 0; nt < 4; nt++) {
        int tr = wn + nt * 16 + l16;
        #pragma unroll
        for (int ks = 0; ks < 2; ks++)
            boff[nt][ks] = tr * 128 + (((ks * 4 + quad) - (tr & 7)) & 7) * 16;
    }

    i32x4 acc[4][4];
    #pragma unroll
    for (int i = 0; i < 4; i++)
        #pragma unroll
        for (int j = 0; j < 4; j++) acc[i][j] = (i32x4)0;

    for (int kk = 0; kk < D2; kk += 128) {
        #pragma unroll
        for (int r = 0; r < 4; r++) {
            gld16(pa[r] + kk, As + r * 4096 + w * 1024);
            gld16(pb[r] + kk, Bs + r * 4096 + w * 1024);
        }
        i32x4 mv0 = *(const i32x4*)(mrow + kk + quad * 16);
        i32x4 mv1 = *(const i32x4*)(mrow + kk + 64 + quad * 16);
        __syncthreads();
        #pragma unroll
        for (int ks = 0; ks < 2; ks++) {
            i32x4 mv = ks ? mv1 : mv0;
            i32x4 a[4], bq[4];
            #pragma unroll
            for (int mt = 0; mt < 4; mt++)
                a[mt] = *(const i32x4*)(As + aoff[mt][ks]);
            #pragma unroll
            for (int nt = 0; nt < 4; nt++)
                bq[nt] = (*(const i32x4*)(Bs + boff[nt][ks])) & mv;
            #pragma unroll
            for (int mt = 0; mt < 4; mt++)
                #pragma unroll
                for (int nt = 0; nt < 4; nt++)
                    acc[mt][nt] = __builtin_amdgcn_mfma_i32_16x16x64_i8(
                        a[mt], bq[nt], acc[mt][nt], 0, 0, 0);
        }
        __syncthreads();
    }

    float saCQ[4];
    #pragma unroll
    for (int nt = 0; nt < 4; nt++)
        saCQ[nt] = saq[n0 + wn + nt * 16 + l16] * CQ;

    #pragma unroll
    for (int mt = 0; mt < 4; mt++)
        #pragma unroll
        for (int r = 0; r < 4; r++) {
            float s = 0.f;
            #pragma unroll
            for (int nt = 0; nt < 4; nt++) {
                float v = (float)acc[mt][nt][r] * saCQ[nt];
                s += v * v;
            }
            s += __shfl_down(s, 8, 64);
            s += __shfl_down(s, 4, 64);
            s += __shfl_down(s, 2, 64);
            s += __shfl_down(s, 1, 64);
            if (l16 == 0) {
                int p = m0 + wm + mt * 16 + quad * 4 + r;
                float s3 = s3q[p];
                atomicAdd(&norm3[(size_t)b * D3 + p], s * s3 * s3);
            }
        }
}

// ---- per-batch k-smallest sum; dist2/dist3 inline; atomic to out -----------
__global__ __launch_bounds__(256) void k_topk(
    const float* __restrict__ dists,    // [B][D1] dist1 only
    const float* __restrict__ z2, const float* __restrict__ norm2,
    const float* __restrict__ z3, const float* __restrict__ norm3,
    const int* __restrict__ kp, float* __restrict__ outp) {
    __shared__ unsigned long long wmin[4];
    int b = blockIdx.x, t = threadIdx.x;
    float lv[7];
    #pragma unroll
    for (int j = 0; j < 4; j++) lv[j] = dists[(size_t)b * D1 + t + 256 * j];
    #pragma unroll
    for (int j = 4; j < 6; j++) {
        int o = t + 256 * j - 1024;
        lv[j] = fabsf(z2[(size_t)b * D2 + o]) / sqrtf(norm2[(size_t)b * D2 + o]);
    }
    lv[6] = fabsf(z3[(size_t)b * D3 + t]) / sqrtf(norm3[(size_t)b * D3 + t]);
    int k = *kp;
    if (k > NDIST) k = NDIST;
    float sum = 0.f;
    for (int it = 0; it < k; it++) {
        float mv = lv[0]; int mj = 0;
        #pragma unroll
        for (int j = 1; j < 7; j++)
            if (lv[j] < mv) { mv = lv[j]; mj = j; }
        unsigned long long key =
            ((unsigned long long)__float_as_uint(mv) << 32) | (unsigned)(t * 8 + mj);
        #pragma unroll
        for (int off = 32; off > 0; off >>= 1) {
            unsigned long long o = __shfl_down(key, off, 64);
            if (o < key) key = o;
        }
        if ((t & 63) == 0) wmin[t >> 6] = key;
        __syncthreads();
        unsigned long long k0 = wmin[0];
        #pragma unroll
        for (int ww = 1; ww < 4; ww++) if (wmin[ww] < k0) k0 = wmin[ww];
        sum += __uint_as_float((unsigned)(k0 >> 32));
        int wt = (int)((k0 & 0xFFFu) >> 3), wj = (int)(k0 & 7u);
        if (t == wt) lv[wj] = FLT_MAX;
        __syncthreads();
    }
    if (t == 0) atomicAdd(outp, sum);
}

extern "C" void kernel_launch(void* const* d_in, const int* in_sizes, int n_in,
                              void* d_out, int out_size, void* d_ws, size_t ws_size,
                              hipStream_t stream) {
    const float* x  = (const float*)d_in[0];
    const float* W1 = (const float*)d_in[1];
    const float* b1 = (const float*)d_in[2];
    const float* W2 = (const float*)d_in[3];
    const float* b2 = (const float*)d_in[4];
    const float* W3 = (const float*)d_in[5];
    const float* b3 = (const float*)d_in[6];
    const int*   kp = (const int*)d_in[7];
    float* outp = (float*)d_out;

    float* fp = (float*)d_ws;
    float* rn1     = fp;                          fp += D1;
    float* z2      = fp;                          fp += (size_t)B * D2;
    float* z3      = fp;                          fp += (size_t)B * D3;
    float* dists   = fp;                          fp += (size_t)B * D1;
    float* norm2   = fp;                          fp += (size_t)B * D2;   // norm2,norm3 contiguous
    float* norm3   = fp;                          fp += (size_t)B * D3;
    float* saq     = fp;                          fp += D;
    float* sbq     = fp;                          fp += D2;
    float* s3q     = fp;                          fp += D3;
    unsigned short* up = (unsigned short*)fp;
    unsigned short* W2hi  = up;  up += (size_t)D2 * D1;
    unsigned short* W3hi  = up;  up += (size_t)D3 * D2;
    unsigned short* xhi   = up;  up += (size_t)B * D;
    unsigned short* W1hi  = up;  up += (size_t)D1 * D;
    unsigned short* h1hi  = up;  up += (size_t)B * D1;
    unsigned short* h2hi  = up;  up += (size_t)B * D2;
    signed char*    cp = (signed char*)up;
    signed char*    W1Ti8 = cp;  cp += (size_t)D * D1;
    signed char*    W2i8  = cp;  cp += (size_t)D2 * D1;
    signed char*    W3i8  = cp;  cp += (size_t)D3 * D2;
    unsigned char*  m1q   = (unsigned char*)cp;  cp += (size_t)B * D1;
    unsigned char*  m2q   = (unsigned char*)cp;  cp += (size_t)B * D2;
    signed char*    qV2   = cp;

    size_t base_bytes = (size_t)((char*)qV2 - (char*)d_ws);
    int CH = 8;
    const int cands[6] = {256, 128, 64, 32, 16, 8};
    for (int c = 0; c < 6; c++) {
        size_t need = base_bytes + (size_t)cands[c] * D * D2;
        if (need <= ws_size) { CH = cands[c]; break; }
    }

    k_prep<<<2184, 256, 0, stream>>>(x, W1, W2, W3, norm2, outp,
                                     xhi, W1hi, W2hi, W3hi,
                                     W1Ti8, saq, W2i8, sbq, W3i8, s3q, rn1);

    k_l1<<<dim3(B / 64, D1 / 64), 256, 0, stream>>>(xhi, W1hi, b1, rn1,
                                                    dists, m1q, h1hi);
    k_l2<<<dim3(B / 64, D2 / 64), 256, 0, stream>>>(h1hi, W2hi, b2, z2, m2q, h2hi);
    k_l3<<<dim3(B / 64, D3 / 64), 256, 0, stream>>>(h2hi, W3hi, b3, z3);

    for (int b0 = 0; b0 < B; b0 += CH) {
        k_gemm1<<<dim3(D2 / 128, D / 128, CH), 256, 0, stream>>>(
            W2i8, W1Ti8, m1q, saq, sbq, qV2, norm2, b0);
        k_gemm2<<<dim3(D3 / 128, D / 128, CH), 256, 0, stream>>>(
            W3i8, qV2, m2q, saq, s3q, norm3, b0);
    }

    k_topk<<<B, 256, 0, stream>>>(dists, z2, norm2, z3, norm3, kp, outp);
}

// Round 8
// 205.980 us; speedup vs baseline: 1.1303x; 1.1303x over previous
//
#include <hip/hip_runtime.h>
#include <math.h>
#include <float.h>

#define B   256
#define D   256
#define D1  1024
#define D2  512
#define D3  256
#define NDIST (D1 + D2 + D3)   // 1792
#define CQ  2.0f               // qV2 static scale multiplier (step = sa[d]*CQ)

typedef __attribute__((ext_vector_type(8))) short short8;
typedef __attribute__((ext_vector_type(4))) float f32x4;
typedef __attribute__((ext_vector_type(4))) int   i32x4;

__device__ __forceinline__ float waveReduceSum(float v) {
    #pragma unroll
    for (int off = 32; off > 0; off >>= 1)
        v += __shfl_down(v, off, 64);
    return v;
}
__device__ __forceinline__ float waveReduceMax(float v) {
    #pragma unroll
    for (int off = 32; off > 0; off >>= 1)
        v = fmaxf(v, __shfl_down(v, off, 64));
    return v;
}

__device__ __forceinline__ unsigned short f2bf(float f) {
    unsigned int u = __float_as_uint(f);
    u = (u + 0x7FFFu + ((u >> 16) & 1u)) >> 16;   // RNE
    return (unsigned short)u;
}
__device__ __forceinline__ float bf2f(unsigned short h) {
    return __uint_as_float(((unsigned int)h) << 16);
}
__device__ __forceinline__ void gld16(const void* g, void* l) {
    __builtin_amdgcn_global_load_lds(
        (const __attribute__((address_space(1))) unsigned int*)g,
        (__attribute__((address_space(3))) unsigned int*)l, 16, 0, 0);
}

// bf16 tile swizzle helpers (R4-proven: 0 bank conflicts)
__device__ __forceinline__ int swz_src(int row, int lane) {
    return ((lane & 3) + ((row >> 1) & 3)) & 3;
}
__device__ __forceinline__ int swz_frag(int row, int quad) {
    return row * 32 + (((quad - ((row >> 1) & 3)) & 3) * 8);
}

// ---- mega prep: zero norms+out, hi/lo splits, i8 quant of W1T/W2/W3, rn1 ---
__global__ __launch_bounds__(256) void k_prep(
    const float* __restrict__ x,  const float* __restrict__ W1,
    const float* __restrict__ W2, const float* __restrict__ W3,
    float* __restrict__ norms,                 // norm2||norm3, 196608 floats
    float* __restrict__ outp,
    unsigned short* __restrict__ xhi,  unsigned short* __restrict__ xlo,
    unsigned short* __restrict__ W1hi, unsigned short* __restrict__ W1lo,
    unsigned short* __restrict__ W2hi, unsigned short* __restrict__ W2lo,
    unsigned short* __restrict__ W3hi, unsigned short* __restrict__ W3lo,
    signed char* __restrict__ W1Ti8, float* __restrict__ saq,
    signed char* __restrict__ W2i8,  float* __restrict__ sbq,
    signed char* __restrict__ W3i8,  float* __restrict__ s3q,
    float* __restrict__ rn1) {
    int blk = blockIdx.x;
    int t = threadIdx.x;
    if (blk < 768) {                                   // zero norms (+ out)
        if (blk == 0 && t == 0) outp[0] = 0.f;
        norms[blk * 256 + t] = 0.f;
        return;
    }
    if (blk < 1728) {                                  // hi/lo splits
        int i4 = ((blk - 768) * 256 + t) * 4;
        const float* src; unsigned short *hi, *lo; int off;
        if (i4 < 65536)       { src = x;  hi = xhi;  lo = xlo;  off = i4; }
        else if (i4 < 327680) { src = W1; hi = W1hi; lo = W1lo; off = i4 - 65536; }
        else if (i4 < 851968) { src = W2; hi = W2hi; lo = W2lo; off = i4 - 327680; }
        else                  { src = W3; hi = W3hi; lo = W3lo; off = i4 - 851968; }
        float4 v = *(const float4*)(src + off);
        ushort4 h, l;
        h.x = f2bf(v.x); l.x = f2bf(v.x - bf2f(h.x));
        h.y = f2bf(v.y); l.y = f2bf(v.y - bf2f(h.y));
        h.z = f2bf(v.z); l.z = f2bf(v.z - bf2f(h.z));
        h.w = f2bf(v.w); l.w = f2bf(v.w - bf2f(h.w));
        *(ushort4*)(hi + off) = h;
        *(ushort4*)(lo + off) = l;
        return;
    }
    if (blk < 1760) {                                  // W1 col quant -> W1Ti8
        int ty = t >> 5, tx = t & 31;
        int d = (blk - 1728) * 8 + ty;
        float m = 0.f;
        for (int i = tx; i < D1; i += 32) m = fmaxf(m, fabsf(W1[(size_t)i * D + d]));
        #pragma unroll
        for (int off = 16; off > 0; off >>= 1) m = fmaxf(m, __shfl_down(m, off, 32));
        m = __shfl(m, 0, 32);
        m = fmaxf(m, 1e-20f);
        if (tx == 0) saq[d] = m / 127.f;
        float inv = 127.f / m;
        for (int i = tx; i < D1; i += 32) {
            int q = __float2int_rn(W1[(size_t)i * D + d] * inv);
            W1Ti8[(size_t)d * D1 + i] = (signed char)q;
        }
        return;
    }
    if (blk < 1888) {                                  // W2 row quant
        int o = (blk - 1760) * 4 + (t >> 6);
        int l = t & 63;
        const float* row = W2 + (size_t)o * D1;
        float m = 0.f;
        for (int tt = l; tt < D1; tt += 64) m = fmaxf(m, fabsf(row[tt]));
        m = waveReduceMax(m);
        m = __shfl(m, 0, 64);
        m = fmaxf(m, 1e-20f);
        if (l == 0) sbq[o] = m / 127.f;
        float inv = 127.f / m;
        for (int tt = l; tt < D1; tt += 64)
            W2i8[(size_t)o * D1 + tt] = (signed char)__float2int_rn(row[tt] * inv);
        return;
    }
    if (blk < 1952) {                                  // W3 row quant
        int p = (blk - 1888) * 4 + (t >> 6);
        int l = t & 63;
        const float* row = W3 + (size_t)p * D2;
        float m = 0.f;
        for (int tt = l; tt < D2; tt += 64) m = fmaxf(m, fabsf(row[tt]));
        m = waveReduceMax(m);
        m = __shfl(m, 0, 64);
        m = fmaxf(m, 1e-20f);
        if (l == 0) s3q[p] = m / 127.f;
        float inv = 127.f / m;
        for (int tt = l; tt < D2; tt += 64)
            W3i8[(size_t)p * D2 + tt] = (signed char)__float2int_rn(row[tt] * inv);
        return;
    }
    {                                                  // rn1 (W1 row norms)
        int gw = (blk - 1952) * 4 + (t >> 6);
        int lane = t & 63;
        const float* row = W1 + (size_t)gw * D;
        float s = 0.f;
        for (int tt = lane; tt < D; tt += 64) { float v = row[tt]; s += v * v; }
        s = waveReduceSum(s);
        if (lane == 0) rn1[gw] = sqrtf(s);
    }
}

// ---- compensated bf16 MFMA mainloop for a 64x64 tile, C = A @ B^T ----------
template <int KD>
__device__ __forceinline__ void mfma3_64(
    const unsigned short* __restrict__ Ahi, const unsigned short* __restrict__ Alo,
    const unsigned short* __restrict__ Bhi, const unsigned short* __restrict__ Blo,
    int m0, int n0, unsigned short* sm, f32x4 acc[2][2]) {
    int tid = threadIdx.x;
    int l = tid & 63, w = tid >> 6;
    int rsub = l >> 2;
    int quad = l >> 4, l16 = l & 15;
    int wm = (w >> 1) * 32, wn = (w & 1) * 32;
    unsigned short* sAh = sm;
    unsigned short* sAl = sm + 2048;
    unsigned short* sBh = sm + 4096;
    unsigned short* sBl = sm + 6144;
    ptrdiff_t dA = Alo - Ahi, dB = Blo - Bhi;
    int rloc = w * 16 + rsub;
    int c = swz_src(rloc, l);
    const unsigned short* pa = Ahi + (size_t)(m0 + rloc) * KD + c * 8;
    const unsigned short* pb = Bhi + (size_t)(n0 + rloc) * KD + c * 8;
    int aoff[2], boff[2];
    #pragma unroll
    for (int mt = 0; mt < 2; mt++) aoff[mt] = swz_frag(wm + mt * 16 + l16, quad);
    #pragma unroll
    for (int nt = 0; nt < 2; nt++) boff[nt] = swz_frag(wn + nt * 16 + l16, quad);
    for (int kk = 0; kk < KD; kk += 32) {
        gld16(pa + kk,      sAh + w * 512);
        gld16(pa + dA + kk, sAl + w * 512);
        gld16(pb + kk,      sBh + w * 512);
        gld16(pb + dB + kk, sBl + w * 512);
        __syncthreads();
        short8 ah[2], al[2], bh[2], bl[2];
        #pragma unroll
        for (int mt = 0; mt < 2; mt++) {
            ah[mt] = *(const short8*)(sAh + aoff[mt]);
            al[mt] = *(const short8*)(sAl + aoff[mt]);
        }
        #pragma unroll
        for (int nt = 0; nt < 2; nt++) {
            bh[nt] = *(const short8*)(sBh + boff[nt]);
            bl[nt] = *(const short8*)(sBl + boff[nt]);
        }
        #pragma unroll
        for (int mt = 0; mt < 2; mt++)
            #pragma unroll
            for (int nt = 0; nt < 2; nt++) {
                acc[mt][nt] = __builtin_amdgcn_mfma_f32_16x16x32_bf16(ah[mt], bh[nt], acc[mt][nt], 0, 0, 0);
                acc[mt][nt] = __builtin_amdgcn_mfma_f32_16x16x32_bf16(ah[mt], bl[nt], acc[mt][nt], 0, 0, 0);
                acc[mt][nt] = __builtin_amdgcn_mfma_f32_16x16x32_bf16(al[mt], bh[nt], acc[mt][nt], 0, 0, 0);
            }
        __syncthreads();
    }
}

// ---- layer 1: z1 -> dist1 (stride D1), m1q bytes, h1 hi/lo -----------------
__global__ __launch_bounds__(256) void k_l1(
    const unsigned short* __restrict__ xhi,  const unsigned short* __restrict__ xlo,
    const unsigned short* __restrict__ W1hi, const unsigned short* __restrict__ W1lo,
    const float* __restrict__ b1, const float* __restrict__ rn1,
    float* __restrict__ dists, unsigned char* __restrict__ m1q,
    unsigned short* __restrict__ h1hi, unsigned short* __restrict__ h1lo) {
    __shared__ __align__(16) unsigned short sm[8192];
    int m0 = blockIdx.x * 64, n0 = blockIdx.y * 64;
    f32x4 acc[2][2] = {};
    mfma3_64<D>(xhi, xlo, W1hi, W1lo, m0, n0, sm, acc);
    int l = threadIdx.x & 63, w = threadIdx.x >> 6;
    int quad = l >> 4, l16 = l & 15;
    int wm = (w >> 1) * 32, wn = (w & 1) * 32;
    #pragma unroll
    for (int mt = 0; mt < 2; mt++)
        #pragma unroll
        for (int nt = 0; nt < 2; nt++) {
            int n = n0 + wn + nt * 16 + l16;
            float bv = b1[n], rv = rn1[n];
            #pragma unroll
            for (int r = 0; r < 4; r++) {
                int m = m0 + wm + mt * 16 + quad * 4 + r;
                float z = acc[mt][nt][r] + bv;
                size_t idx = (size_t)m * D1 + n;
                dists[idx] = fabsf(z) / rv;
                m1q[idx] = (z > 0.f) ? 0xFFu : 0u;
                float h = z > 0.f ? z : 0.f;
                unsigned short hh = f2bf(h);
                h1hi[idx] = hh;
                h1lo[idx] = f2bf(h - bf2f(hh));
            }
        }
}

// ---- layer 2: also emits m2q bytes -----------------------------------------
__global__ __launch_bounds__(256) void k_l2(
    const unsigned short* __restrict__ h1hi, const unsigned short* __restrict__ h1lo,
    const unsigned short* __restrict__ W2hi, const unsigned short* __restrict__ W2lo,
    const float* __restrict__ b2, float* __restrict__ z2,
    unsigned char* __restrict__ m2q,
    unsigned short* __restrict__ h2hi, unsigned short* __restrict__ h2lo) {
    __shared__ __align__(16) unsigned short sm[8192];
    int m0 = blockIdx.x * 64, n0 = blockIdx.y * 64;
    f32x4 acc[2][2] = {};
    mfma3_64<D1>(h1hi, h1lo, W2hi, W2lo, m0, n0, sm, acc);
    int l = threadIdx.x & 63, w = threadIdx.x >> 6;
    int quad = l >> 4, l16 = l & 15;
    int wm = (w >> 1) * 32, wn = (w & 1) * 32;
    #pragma unroll
    for (int mt = 0; mt < 2; mt++)
        #pragma unroll
        for (int nt = 0; nt < 2; nt++) {
            int n = n0 + wn + nt * 16 + l16;
            float bv = b2[n];
            #pragma unroll
            for (int r = 0; r < 4; r++) {
                int m = m0 + wm + mt * 16 + quad * 4 + r;
                float z = acc[mt][nt][r] + bv;
                size_t idx = (size_t)m * D2 + n;
                z2[idx] = z;
                m2q[idx] = (z > 0.f) ? 0xFFu : 0u;
                float h = z > 0.f ? z : 0.f;
                unsigned short hh = f2bf(h);
                h2hi[idx] = hh;
                h2lo[idx] = f2bf(h - bf2f(hh));
            }
        }
}

// ---- layer 3 ---------------------------------------------------------------
__global__ __launch_bounds__(256) void k_l3(
    const unsigned short* __restrict__ h2hi, const unsigned short* __restrict__ h2lo,
    const unsigned short* __restrict__ W3hi, const unsigned short* __restrict__ W3lo,
    const float* __restrict__ b3, float* __restrict__ z3) {
    __shared__ __align__(16) unsigned short sm[8192];
    int m0 = blockIdx.x * 64, n0 = blockIdx.y * 64;
    f32x4 acc[2][2] = {};
    mfma3_64<D2>(h2hi, h2lo, W3hi, W3lo, m0, n0, sm, acc);
    int l = threadIdx.x & 63, w = threadIdx.x >> 6;
    int quad = l >> 4, l16 = l & 15;
    int wm = (w >> 1) * 32, wn = (w & 1) * 32;
    #pragma unroll
    for (int mt = 0; mt < 2; mt++)
        #pragma unroll
        for (int nt = 0; nt < 2; nt++) {
            int n = n0 + wn + nt * 16 + l16;
            float bv = b3[n];
            #pragma unroll
            for (int r = 0; r < 4; r++) {
                int m = m0 + wm + mt * 16 + quad * 4 + r;
                z3[(size_t)m * D3 + n] = acc[mt][nt][r] + bv;
            }
        }
}

// ---- GEMM1 (i8): V2T[d][o] = sa[d]*sb[o]*sum_i (m1&qW1T)[d][i]*qW2[o][i] ---
// R5 orientation (M=d, N=o, mask on A) + int8 qV2[d][o] byte-store epilogue.
__global__ __launch_bounds__(256) void k_gemm1(
    const signed char* __restrict__ W1Ti8,   // [256][1024]  A rows (d)
    const signed char* __restrict__ W2i8,    // [512][1024]  B rows (o)
    const unsigned char* __restrict__ m1q,   // [B][1024]
    const float* __restrict__ saq,           // [256]
    const float* __restrict__ sbq,           // [512]
    signed char* __restrict__ qV2,           // [CH][256][512] (d-major)
    float* __restrict__ norm2,               // [B][512]
    int b0) {
    __shared__ __align__(16) signed char As[8192];   // 128 rows x 64B
    __shared__ __align__(16) signed char Bs[8192];
    int m0 = blockIdx.x * 128;        // d
    int o0 = blockIdx.y * 128;        // o
    int bc = blockIdx.z;
    int b = b0 + bc;
    int tid = threadIdx.x;
    int l = tid & 63, w = tid >> 6;
    int rsub = l >> 2, cq = l & 3;
    int quad = l >> 4, l16 = l & 15;
    int wm = (w >> 1) * 64, wn = (w & 1) * 64;
    const unsigned char* mrow = m1q + (size_t)b * D1;

    const signed char* pa[2];
    const signed char* pb[2];
    #pragma unroll
    for (int r = 0; r < 2; r++) {
        int rloc = w * 32 + r * 16 + rsub;
        int c = (cq + ((rsub >> 1) & 3)) & 3;
        pa[r] = W1Ti8 + (size_t)(m0 + rloc) * D1 + c * 16;
        pb[r] = W2i8 + (size_t)(o0 + rloc) * D1 + c * 16;
    }
    int hq = (l16 >> 1) & 3;
    int slot = ((quad - hq) & 3) * 16;
    int aoff[4], boff[4];
    #pragma unroll
    for (int mt = 0; mt < 4; mt++) aoff[mt] = (wm + mt * 16 + l16) * 64 + slot;
    #pragma unroll
    for (int nt = 0; nt < 4; nt++) boff[nt] = (wn + nt * 16 + l16) * 64 + slot;

    i32x4 acc[4][4];
    #pragma unroll
    for (int i = 0; i < 4; i++)
        #pragma unroll
        for (int j = 0; j < 4; j++) acc[i][j] = (i32x4)0;

    for (int kk = 0; kk < D1; kk += 64) {
        #pragma unroll
        for (int r = 0; r < 2; r++) {
            gld16(pa[r] + kk, As + w * 2048 + r * 1024);
            gld16(pb[r] + kk, Bs + w * 2048 + r * 1024);
        }
        i32x4 mv = *(const i32x4*)(mrow + kk + quad * 16);
        __syncthreads();
        i32x4 a[4], bq[4];
        #pragma unroll
        for (int mt = 0; mt < 4; mt++)
            a[mt] = (*(const i32x4*)(As + aoff[mt])) & mv;
        #pragma unroll
        for (int nt = 0; nt < 4; nt++)
            bq[nt] = *(const i32x4*)(Bs + boff[nt]);
        #pragma unroll
        for (int mt = 0; mt < 4; mt++)
            #pragma unroll
            for (int nt = 0; nt < 4; nt++)
                acc[mt][nt] = __builtin_amdgcn_mfma_i32_16x16x64_i8(
                    a[mt], bq[nt], acc[mt][nt], 0, 0, 0);
        __syncthreads();
    }

    // scales: d per (mt,r) rows; o per (nt) cols
    float sad[4][4];
    #pragma unroll
    for (int mt = 0; mt < 4; mt++)
        #pragma unroll
        for (int r = 0; r < 4; r++)
            sad[mt][r] = saq[m0 + wm + mt * 16 + quad * 4 + r];
    float sbv[4], sbdq[4];
    #pragma unroll
    for (int nt = 0; nt < 4; nt++) {
        sbv[nt] = sbq[o0 + wn + nt * 16 + l16];
        sbdq[nt] = sbv[nt] * (1.0f / CQ);
    }

    // norm2[o] += sum_d V2^2  (V2 = acc*sa*sb); R5's cheap reduce
    #pragma unroll
    for (int nt = 0; nt < 4; nt++) {
        float s = 0.f;
        #pragma unroll
        for (int mt = 0; mt < 4; mt++)
            #pragma unroll
            for (int r = 0; r < 4; r++) {
                float v = (float)acc[mt][nt][r] * sad[mt][r] * sbv[nt];
                s += v * v;
            }
        s += __shfl_down(s, 32, 64);
        s += __shfl_down(s, 16, 64);
        if (l < 16)
            atomicAdd(&norm2[(size_t)b * D2 + o0 + wn + nt * 16 + l], s);
    }

    // qV2[d][o] int8 byte stores: q = round(acc*sb[o]/CQ)  (dequant: *sa[d]*CQ)
    signed char* qb = qV2 + (size_t)bc * (D * D2);
    #pragma unroll
    for (int mt = 0; mt < 4; mt++) {
        int dbase = m0 + wm + mt * 16 + quad * 4;
        #pragma unroll
        for (int r = 0; r < 4; r++)
            #pragma unroll
            for (int nt = 0; nt < 4; nt++) {
                int o = o0 + wn + nt * 16 + l16;
                int qi = __float2int_rn((float)acc[mt][nt][r] * sbdq[nt]);
                qi = max(-127, min(127, qi));
                qb[(size_t)(dbase + r) * D2 + o] = (signed char)qi;
            }
    }
}

// ---- GEMM2 (i8): norm3[b][p] += s3[p]^2 * sum_d (saCQ[d]*S3[p][d])^2 -------
// S3[p][d] = sum_o qW3[p][o] * (m2 & qV2)[d][o].  M=p(256),N=d(256),K=o(512).
__global__ __launch_bounds__(256) void k_gemm2(
    const signed char* __restrict__ W3i8,    // [256][512]
    const signed char* __restrict__ qV2,     // [CH][256][512]
    const unsigned char* __restrict__ m2q,   // [B][512]
    const float* __restrict__ saq,           // [256]
    const float* __restrict__ s3q,           // [256]
    float* __restrict__ norm3,               // [B][256]
    int b0) {
    __shared__ __align__(16) signed char As[8192];
    __shared__ __align__(16) signed char Bs[8192];
    int m0 = blockIdx.x * 128;        // p
    int n0 = blockIdx.y * 128;        // d
    int bc = blockIdx.z;
    int b = b0 + bc;
    int tid = threadIdx.x;
    int l = tid & 63, w = tid >> 6;
    int rsub = l >> 2, cq = l & 3;
    int quad = l >> 4, l16 = l & 15;
    int wm = (w >> 1) * 64, wn = (w & 1) * 64;
    const unsigned char* mrow = m2q + (size_t)b * D2;
    const signed char* Bsrc = qV2 + (size_t)bc * (D * D2);

    const signed char* pa[2];
    const signed char* pb[2];
    #pragma unroll
    for (int r = 0; r < 2; r++) {
        int rloc = w * 32 + r * 16 + rsub;
        int c = (cq + ((rsub >> 1) & 3)) & 3;
        pa[r] = W3i8 + (size_t)(m0 + rloc) * D2 + c * 16;
        pb[r] = Bsrc + (size_t)(n0 + rloc) * D2 + c * 16;
    }
    int hq = (l16 >> 1) & 3;
    int slot = ((quad - hq) & 3) * 16;
    int aoff[4], boff[4];
    #pragma unroll
    for (int mt = 0; mt < 4; mt++) aoff[mt] = (wm + mt * 16 + l16) * 64 + slot;
    #pragma unroll
    for (int nt = 0; nt < 4; nt++) boff[nt] = (wn + nt * 16 + l16) * 64 + slot;

    i32x4 acc[4][4];
    #pragma unroll
    for (int i = 0; i < 4; i++)
        #pragma unroll
        for (int j = 0; j < 4; j++) acc[i][j] = (i32x4)0;

    for (int kk = 0; kk < D2; kk += 64) {
        #pragma unroll
        for (int r = 0; r < 2; r++) {
            gld16(pa[r] + kk, As + w * 2048 + r * 1024);
            gld16(pb[r] + kk, Bs + w * 2048 + r * 1024);
        }
        i32x4 mv = *(const i32x4*)(mrow + kk + quad * 16);
        __syncthreads();
        i32x4 a[4], bq[4];
        #pragma unroll
        for (int mt = 0; mt < 4; mt++)
            a[mt] = *(const i32x4*)(As + aoff[mt]);
        #pragma unroll
        for (int nt = 0; nt < 4; nt++)
            bq[nt] = (*(const i32x4*)(Bs + boff[nt])) & mv;
        #pragma unroll
        for (int mt = 0; mt < 4; mt++)
            #pragma unroll
            for (int nt = 0; nt < 4; nt++)
                acc[mt][nt] = __builtin_amdgcn_mfma_i32_16x16x64_i8(
                    a[mt], bq[nt], acc[mt][nt], 0, 0, 0);
        __syncthreads();
    }

    float saCQ[4];
    #pragma unroll
    for (int nt = 0; nt < 4; nt++)
        saCQ[nt] = saq[n0 + wn + nt * 16 + l16] * CQ;

    #pragma unroll
    for (int mt = 0; mt < 4; mt++)
        #pragma unroll
        for (int r = 0; r < 4; r++) {
            float s = 0.f;
            #pragma unroll
            for (int nt = 0; nt < 4; nt++) {
                float v = (float)acc[mt][nt][r] * saCQ[nt];
                s += v * v;
            }
            s += __shfl_down(s, 8, 64);
            s += __shfl_down(s, 4, 64);
            s += __shfl_down(s, 2, 64);
            s += __shfl_down(s, 1, 64);
            if (l16 == 0) {
                int p = m0 + wm + mt * 16 + quad * 4 + r;
                float s3 = s3q[p];
                atomicAdd(&norm3[(size_t)b * D3 + p], s * s3 * s3);
            }
        }
}

// ---- per-batch k-smallest sum; dist2/dist3 inline; atomic to out -----------
__global__ __launch_bounds__(256) void k_topk(
    const float* __restrict__ dists,    // [B][D1] dist1 only
    const float* __restrict__ z2, const float* __restrict__ norm2,
    const float* __restrict__ z3, const float* __restrict__ norm3,
    const int* __restrict__ kp, float* __restrict__ outp) {
    __shared__ unsigned long long wmin[4];
    int b = blockIdx.x, t = threadIdx.x;
    float lv[7];
    #pragma unroll
    for (int j = 0; j < 4; j++) lv[j] = dists[(size_t)b * D1 + t + 256 * j];
    #pragma unroll
    for (int j = 4; j < 6; j++) {
        int o = t + 256 * j - 1024;
        lv[j] = fabsf(z2[(size_t)b * D2 + o]) / sqrtf(norm2[(size_t)b * D2 + o]);
    }
    lv[6] = fabsf(z3[(size_t)b * D3 + t]) / sqrtf(norm3[(size_t)b * D3 + t]);
    int k = *kp;
    if (k > NDIST) k = NDIST;
    float sum = 0.f;
    for (int it = 0; it < k; it++) {
        float mv = lv[0]; int mj = 0;
        #pragma unroll
        for (int j = 1; j < 7; j++)
            if (lv[j] < mv) { mv = lv[j]; mj = j; }
        unsigned long long key =
            ((unsigned long long)__float_as_uint(mv) << 32) | (unsigned)(t * 8 + mj);
        #pragma unroll
        for (int off = 32; off > 0; off >>= 1) {
            unsigned long long o = __shfl_down(key, off, 64);
            if (o < key) key = o;
        }
        if ((t & 63) == 0) wmin[t >> 6] = key;
        __syncthreads();
        unsigned long long k0 = wmin[0];
        #pragma unroll
        for (int ww = 1; ww < 4; ww++) if (wmin[ww] < k0) k0 = wmin[ww];
        sum += __uint_as_float((unsigned)(k0 >> 32));
        int wt = (int)((k0 & 0xFFFu) >> 3), wj = (int)(k0 & 7u);
        if (t == wt) lv[wj] = FLT_MAX;
        __syncthreads();
    }
    if (t == 0) atomicAdd(outp, sum);
}

extern "C" void kernel_launch(void* const* d_in, const int* in_sizes, int n_in,
                              void* d_out, int out_size, void* d_ws, size_t ws_size,
                              hipStream_t stream) {
    const float* x  = (const float*)d_in[0];
    const float* W1 = (const float*)d_in[1];
    const float* b1 = (const float*)d_in[2];
    const float* W2 = (const float*)d_in[3];
    const float* b2 = (const float*)d_in[4];
    const float* W3 = (const float*)d_in[5];
    const float* b3 = (const float*)d_in[6];
    const int*   kp = (const int*)d_in[7];
    float* outp = (float*)d_out;

    float* fp = (float*)d_ws;
    float* rn1     = fp;                          fp += D1;
    float* z2      = fp;                          fp += (size_t)B * D2;
    float* z3      = fp;                          fp += (size_t)B * D3;
    float* dists   = fp;                          fp += (size_t)B * D1;
    float* norm2   = fp;                          fp += (size_t)B * D2;   // norm2,norm3 contiguous
    float* norm3   = fp;                          fp += (size_t)B * D3;
    float* saq     = fp;                          fp += D;
    float* sbq     = fp;                          fp += D2;
    float* s3q     = fp;                          fp += D3;
    unsigned short* up = (unsigned short*)fp;
    unsigned short* W2hi  = up;  up += (size_t)D2 * D1;
    unsigned short* W2lo  = up;  up += (size_t)D2 * D1;
    unsigned short* W3hi  = up;  up += (size_t)D3 * D2;
    unsigned short* W3lo  = up;  up += (size_t)D3 * D2;
    unsigned short* xhi   = up;  up += (size_t)B * D;
    unsigned short* xlo   = up;  up += (size_t)B * D;
    unsigned short* W1hi  = up;  up += (size_t)D1 * D;
    unsigned short* W1lo  = up;  up += (size_t)D1 * D;
    unsigned short* h1hi  = up;  up += (size_t)B * D1;
    unsigned short* h1lo  = up;  up += (size_t)B * D1;
    unsigned short* h2hi  = up;  up += (size_t)B * D2;
    unsigned short* h2lo  = up;  up += (size_t)B * D2;
    signed char*    cp = (signed char*)up;
    signed char*    W1Ti8 = cp;  cp += (size_t)D * D1;
    signed char*    W2i8  = cp;  cp += (size_t)D2 * D1;
    signed char*    W3i8  = cp;  cp += (size_t)D3 * D2;
    unsigned char*  m1q   = (unsigned char*)cp;  cp += (size_t)B * D1;
    unsigned char*  m2q   = (unsigned char*)cp;  cp += (size_t)B * D2;
    signed char*    qV2   = cp;

    size_t base_bytes = (size_t)((char*)qV2 - (char*)d_ws);
    int CH = 8;
    const int cands[6] = {256, 128, 64, 32, 16, 8};
    for (int c = 0; c < 6; c++) {
        size_t need = base_bytes + (size_t)cands[c] * D * D2;
        if (need <= ws_size) { CH = cands[c]; break; }
    }

    k_prep<<<2208, 256, 0, stream>>>(x, W1, W2, W3, norm2, outp,
                                     xhi, xlo, W1hi, W1lo, W2hi, W2lo, W3hi, W3lo,
                                     W1Ti8, saq, W2i8, sbq, W3i8, s3q, rn1);

    k_l1<<<dim3(B / 64, D1 / 64), 256, 0, stream>>>(xhi, xlo, W1hi, W1lo, b1, rn1,
                                                    dists, m1q, h1hi, h1lo);
    k_l2<<<dim3(B / 64, D2 / 64), 256, 0, stream>>>(h1hi, h1lo, W2hi, W2lo, b2,
                                                    z2, m2q, h2hi, h2lo);
    k_l3<<<dim3(B / 64, D3 / 64), 256, 0, stream>>>(h2hi, h2lo, W3hi, W3lo, b3, z3);

    for (int b0 = 0; b0 < B; b0 += CH) {
        k_gemm1<<<dim3(D / 128, D2 / 128, CH), 256, 0, stream>>>(
            W1Ti8, W2i8, m1q, saq, sbq, qV2, norm2, b0);
        k_gemm2<<<dim3(D3 / 128, D / 128, CH), 256, 0, stream>>>(
            W3i8, qV2, m2q, saq, s3q, norm3, b0);
    }

    k_topk<<<B, 256, 0, stream>>>(dists, z2, norm2, z3, norm3, kp, outp);
}

// Round 9
// 192.413 us; speedup vs baseline: 1.2100x; 1.0705x over previous
//
#include <hip/hip_runtime.h>
#include <math.h>
#include <float.h>

#define B   256
#define D   256
#define D1  1024
#define D2  512
#define D3  256
#define NDIST (D1 + D2 + D3)   // 1792
#define CQ  2.0f               // qV2 static scale multiplier (step = sa[d]*CQ)

typedef __attribute__((ext_vector_type(8))) short short8;
typedef __attribute__((ext_vector_type(4))) float f32x4;
typedef __attribute__((ext_vector_type(4))) int   i32x4;

__device__ __forceinline__ float waveReduceSum(float v) {
    #pragma unroll
    for (int off = 32; off > 0; off >>= 1)
        v += __shfl_down(v, off, 64);
    return v;
}
__device__ __forceinline__ float waveReduceMax(float v) {
    #pragma unroll
    for (int off = 32; off > 0; off >>= 1)
        v = fmaxf(v, __shfl_down(v, off, 64));
    return v;
}

__device__ __forceinline__ unsigned short f2bf(float f) {
    unsigned int u = __float_as_uint(f);
    u = (u + 0x7FFFu + ((u >> 16) & 1u)) >> 16;   // RNE
    return (unsigned short)u;
}
__device__ __forceinline__ float bf2f(unsigned short h) {
    return __uint_as_float(((unsigned int)h) << 16);
}
__device__ __forceinline__ void gld16(const void* g, void* l) {
    __builtin_amdgcn_global_load_lds(
        (const __attribute__((address_space(1))) unsigned int*)g,
        (__attribute__((address_space(3))) unsigned int*)l, 16, 0, 0);
}

// bf16 tile swizzle helpers (R4-proven: 0 bank conflicts)
__device__ __forceinline__ int swz_src(int row, int lane) {
    return ((lane & 3) + ((row >> 1) & 3)) & 3;
}
__device__ __forceinline__ int swz_frag(int row, int quad) {
    return row * 32 + (((quad - ((row >> 1) & 3)) & 3) * 8);
}

// ---- mega prep: zero z2/z3/norms/out, hi/lo splits, i8 quants, rn1 ---------
__global__ __launch_bounds__(256) void k_prep(
    const float* __restrict__ x,  const float* __restrict__ W1,
    const float* __restrict__ W2, const float* __restrict__ W3,
    float* __restrict__ zeros,                 // z2||z3||norm2||norm3, 393216 f
    float* __restrict__ outp,
    unsigned short* __restrict__ xhi,  unsigned short* __restrict__ xlo,
    unsigned short* __restrict__ W1hi, unsigned short* __restrict__ W1lo,
    unsigned short* __restrict__ W2hi, unsigned short* __restrict__ W2lo,
    unsigned short* __restrict__ W3hi, unsigned short* __restrict__ W3lo,
    signed char* __restrict__ W1Ti8, float* __restrict__ saq,
    signed char* __restrict__ W2i8,  float* __restrict__ sbq,
    signed char* __restrict__ W3i8,  float* __restrict__ s3q,
    float* __restrict__ rn1) {
    int blk = blockIdx.x;
    int t = threadIdx.x;
    if (blk < 1536) {                                  // zero region (+ out)
        if (blk == 0 && t == 0) outp[0] = 0.f;
        zeros[blk * 256 + t] = 0.f;
        return;
    }
    if (blk < 2496) {                                  // hi/lo splits
        int i4 = ((blk - 1536) * 256 + t) * 4;
        const float* src; unsigned short *hi, *lo; int off;
        if (i4 < 65536)       { src = x;  hi = xhi;  lo = xlo;  off = i4; }
        else if (i4 < 327680) { src = W1; hi = W1hi; lo = W1lo; off = i4 - 65536; }
        else if (i4 < 851968) { src = W2; hi = W2hi; lo = W2lo; off = i4 - 327680; }
        else                  { src = W3; hi = W3hi; lo = W3lo; off = i4 - 851968; }
        float4 v = *(const float4*)(src + off);
        ushort4 h, l;
        h.x = f2bf(v.x); l.x = f2bf(v.x - bf2f(h.x));
        h.y = f2bf(v.y); l.y = f2bf(v.y - bf2f(h.y));
        h.z = f2bf(v.z); l.z = f2bf(v.z - bf2f(h.z));
        h.w = f2bf(v.w); l.w = f2bf(v.w - bf2f(h.w));
        *(ushort4*)(hi + off) = h;
        *(ushort4*)(lo + off) = l;
        return;
    }
    if (blk < 2528) {                                  // W1 col quant -> W1Ti8
        int ty = t >> 5, tx = t & 31;
        int d = (blk - 2496) * 8 + ty;
        float m = 0.f;
        for (int i = tx; i < D1; i += 32) m = fmaxf(m, fabsf(W1[(size_t)i * D + d]));
        #pragma unroll
        for (int off = 16; off > 0; off >>= 1) m = fmaxf(m, __shfl_down(m, off, 32));
        m = __shfl(m, 0, 32);
        m = fmaxf(m, 1e-20f);
        if (tx == 0) saq[d] = m / 127.f;
        float inv = 127.f / m;
        for (int i = tx; i < D1; i += 32) {
            int q = __float2int_rn(W1[(size_t)i * D + d] * inv);
            W1Ti8[(size_t)d * D1 + i] = (signed char)q;
        }
        return;
    }
    if (blk < 2656) {                                  // W2 row quant
        int o = (blk - 2528) * 4 + (t >> 6);
        int l = t & 63;
        const float* row = W2 + (size_t)o * D1;
        float m = 0.f;
        for (int tt = l; tt < D1; tt += 64) m = fmaxf(m, fabsf(row[tt]));
        m = waveReduceMax(m);
        m = __shfl(m, 0, 64);
        m = fmaxf(m, 1e-20f);
        if (l == 0) sbq[o] = m / 127.f;
        float inv = 127.f / m;
        for (int tt = l; tt < D1; tt += 64)
            W2i8[(size_t)o * D1 + tt] = (signed char)__float2int_rn(row[tt] * inv);
        return;
    }
    if (blk < 2720) {                                  // W3 row quant
        int p = (blk - 2656) * 4 + (t >> 6);
        int l = t & 63;
        const float* row = W3 + (size_t)p * D2;
        float m = 0.f;
        for (int tt = l; tt < D2; tt += 64) m = fmaxf(m, fabsf(row[tt]));
        m = waveReduceMax(m);
        m = __shfl(m, 0, 64);
        m = fmaxf(m, 1e-20f);
        if (l == 0) s3q[p] = m / 127.f;
        float inv = 127.f / m;
        for (int tt = l; tt < D2; tt += 64)
            W3i8[(size_t)p * D2 + tt] = (signed char)__float2int_rn(row[tt] * inv);
        return;
    }
    {                                                  // rn1 (W1 row norms)
        int gw = (blk - 2720) * 4 + (t >> 6);
        int lane = t & 63;
        const float* row = W1 + (size_t)gw * D;
        float s = 0.f;
        for (int tt = lane; tt < D; tt += 64) { float v = row[tt]; s += v * v; }
        s = waveReduceSum(s);
        if (lane == 0) rn1[gw] = sqrtf(s);
    }
}

// ---- compensated bf16 MFMA mainloop, 64x64 tile, K range [k0, k0+KL) -------
template <int KD, int KL>
__device__ __forceinline__ void mfma3_64(
    const unsigned short* __restrict__ Ahi, const unsigned short* __restrict__ Alo,
    const unsigned short* __restrict__ Bhi, const unsigned short* __restrict__ Blo,
    int m0, int n0, int k0, unsigned short* sm, f32x4 acc[2][2]) {
    int tid = threadIdx.x;
    int l = tid & 63, w = tid >> 6;
    int rsub = l >> 2;
    int quad = l >> 4, l16 = l & 15;
    int wm = (w >> 1) * 32, wn = (w & 1) * 32;
    unsigned short* sAh = sm;
    unsigned short* sAl = sm + 2048;
    unsigned short* sBh = sm + 4096;
    unsigned short* sBl = sm + 6144;
    ptrdiff_t dA = Alo - Ahi, dB = Blo - Bhi;
    int rloc = w * 16 + rsub;
    int c = swz_src(rloc, l);
    const unsigned short* pa = Ahi + (size_t)(m0 + rloc) * KD + k0 + c * 8;
    const unsigned short* pb = Bhi + (size_t)(n0 + rloc) * KD + k0 + c * 8;
    int aoff[2], boff[2];
    #pragma unroll
    for (int mt = 0; mt < 2; mt++) aoff[mt] = swz_frag(wm + mt * 16 + l16, quad);
    #pragma unroll
    for (int nt = 0; nt < 2; nt++) boff[nt] = swz_frag(wn + nt * 16 + l16, quad);
    for (int kk = 0; kk < KL; kk += 32) {
        gld16(pa + kk,      sAh + w * 512);
        gld16(pa + dA + kk, sAl + w * 512);
        gld16(pb + kk,      sBh + w * 512);
        gld16(pb + dB + kk, sBl + w * 512);
        __syncthreads();
        short8 ah[2], al[2], bh[2], bl[2];
        #pragma unroll
        for (int mt = 0; mt < 2; mt++) {
            ah[mt] = *(const short8*)(sAh + aoff[mt]);
            al[mt] = *(const short8*)(sAl + aoff[mt]);
        }
        #pragma unroll
        for (int nt = 0; nt < 2; nt++) {
            bh[nt] = *(const short8*)(sBh + boff[nt]);
            bl[nt] = *(const short8*)(sBl + boff[nt]);
        }
        #pragma unroll
        for (int mt = 0; mt < 2; mt++)
            #pragma unroll
            for (int nt = 0; nt < 2; nt++) {
                acc[mt][nt] = __builtin_amdgcn_mfma_f32_16x16x32_bf16(ah[mt], bh[nt], acc[mt][nt], 0, 0, 0);
                acc[mt][nt] = __builtin_amdgcn_mfma_f32_16x16x32_bf16(ah[mt], bl[nt], acc[mt][nt], 0, 0, 0);
                acc[mt][nt] = __builtin_amdgcn_mfma_f32_16x16x32_bf16(al[mt], bh[nt], acc[mt][nt], 0, 0, 0);
            }
        __syncthreads();
    }
}

// ---- layer 1: z1 -> dist1 (stride D1), m1q bytes, h1 hi/lo (fused) ---------
__global__ __launch_bounds__(256) void k_l1(
    const unsigned short* __restrict__ xhi,  const unsigned short* __restrict__ xlo,
    const unsigned short* __restrict__ W1hi, const unsigned short* __restrict__ W1lo,
    const float* __restrict__ b1, const float* __restrict__ rn1,
    float* __restrict__ dists, unsigned char* __restrict__ m1q,
    unsigned short* __restrict__ h1hi, unsigned short* __restrict__ h1lo) {
    __shared__ __align__(16) unsigned short sm[8192];
    int m0 = blockIdx.x * 64, n0 = blockIdx.y * 64;
    f32x4 acc[2][2] = {};
    mfma3_64<D, D>(xhi, xlo, W1hi, W1lo, m0, n0, 0, sm, acc);
    int l = threadIdx.x & 63, w = threadIdx.x >> 6;
    int quad = l >> 4, l16 = l & 15;
    int wm = (w >> 1) * 32, wn = (w & 1) * 32;
    #pragma unroll
    for (int mt = 0; mt < 2; mt++)
        #pragma unroll
        for (int nt = 0; nt < 2; nt++) {
            int n = n0 + wn + nt * 16 + l16;
            float bv = b1[n], rv = rn1[n];
            #pragma unroll
            for (int r = 0; r < 4; r++) {
                int m = m0 + wm + mt * 16 + quad * 4 + r;
                float z = acc[mt][nt][r] + bv;
                size_t idx = (size_t)m * D1 + n;
                dists[idx] = fabsf(z) / rv;
                m1q[idx] = (z > 0.f) ? 0xFFu : 0u;
                float h = z > 0.f ? z : 0.f;
                unsigned short hh = f2bf(h);
                h1hi[idx] = hh;
                h1lo[idx] = f2bf(h - bf2f(hh));
            }
        }
}

// ---- layer 2 phase A: split-K partial z2 (atomic, no bias) -----------------
__global__ __launch_bounds__(256) void k_l2a(
    const unsigned short* __restrict__ h1hi, const unsigned short* __restrict__ h1lo,
    const unsigned short* __restrict__ W2hi, const unsigned short* __restrict__ W2lo,
    float* __restrict__ z2) {
    __shared__ __align__(16) unsigned short sm[8192];
    int m0 = blockIdx.x * 64, n0 = blockIdx.y * 64, k0 = blockIdx.z * 256;
    f32x4 acc[2][2] = {};
    mfma3_64<D1, 256>(h1hi, h1lo, W2hi, W2lo, m0, n0, k0, sm, acc);
    int l = threadIdx.x & 63, w = threadIdx.x >> 6;
    int quad = l >> 4, l16 = l & 15;
    int wm = (w >> 1) * 32, wn = (w & 1) * 32;
    #pragma unroll
    for (int mt = 0; mt < 2; mt++)
        #pragma unroll
        for (int nt = 0; nt < 2; nt++) {
            int n = n0 + wn + nt * 16 + l16;
            #pragma unroll
            for (int r = 0; r < 4; r++) {
                int m = m0 + wm + mt * 16 + quad * 4 + r;
                atomicAdd(&z2[(size_t)m * D2 + n], acc[mt][nt][r]);
            }
        }
}

// ---- layer 2 phase B: bias + m2q + h2 hi/lo --------------------------------
__global__ __launch_bounds__(256) void k_l2b(
    const float* __restrict__ b2, float* __restrict__ z2,
    unsigned char* __restrict__ m2q,
    unsigned short* __restrict__ h2hi, unsigned short* __restrict__ h2lo) {
    int idx = blockIdx.x * 256 + threadIdx.x;     // B*D2
    int n = idx & (D2 - 1);
    float z = z2[idx] + b2[n];
    z2[idx] = z;
    m2q[idx] = (z > 0.f) ? 0xFFu : 0u;
    float h = z > 0.f ? z : 0.f;
    unsigned short hh = f2bf(h);
    h2hi[idx] = hh;
    h2lo[idx] = f2bf(h - bf2f(hh));
}

// ---- layer 3 phase A: split-K partial z3 (atomic, no bias) -----------------
__global__ __launch_bounds__(256) void k_l3a(
    const unsigned short* __restrict__ h2hi, const unsigned short* __restrict__ h2lo,
    const unsigned short* __restrict__ W3hi, const unsigned short* __restrict__ W3lo,
    float* __restrict__ z3) {
    __shared__ __align__(16) unsigned short sm[8192];
    int m0 = blockIdx.x * 64, n0 = blockIdx.y * 64, k0 = blockIdx.z * 256;
    f32x4 acc[2][2] = {};
    mfma3_64<D2, 256>(h2hi, h2lo, W3hi, W3lo, m0, n0, k0, sm, acc);
    int l = threadIdx.x & 63, w = threadIdx.x >> 6;
    int quad = l >> 4, l16 = l & 15;
    int wm = (w >> 1) * 32, wn = (w & 1) * 32;
    #pragma unroll
    for (int mt = 0; mt < 2; mt++)
        #pragma unroll
        for (int nt = 0; nt < 2; nt++) {
            int n = n0 + wn + nt * 16 + l16;
            #pragma unroll
            for (int r = 0; r < 4; r++) {
                int m = m0 + wm + mt * 16 + quad * 4 + r;
                atomicAdd(&z3[(size_t)m * D3 + n], acc[mt][nt][r]);
            }
        }
}

// ---- layer 3 phase B: bias --------------------------------------------------
__global__ __launch_bounds__(256) void k_l3b(
    const float* __restrict__ b3, float* __restrict__ z3) {
    int idx = blockIdx.x * 256 + threadIdx.x;     // B*D3
    z3[idx] = z3[idx] + b3[idx & (D3 - 1)];
}

// ---- GEMM1 (i8, BK=128): V2T[d][o] via R5/R8 orientation (mask on A) -------
__global__ __launch_bounds__(256) void k_gemm1(
    const signed char* __restrict__ W1Ti8,   // [256][1024]  A rows (d)
    const signed char* __restrict__ W2i8,    // [512][1024]  B rows (o)
    const unsigned char* __restrict__ m1q,   // [B][1024]
    const float* __restrict__ saq,           // [256]
    const float* __restrict__ sbq,           // [512]
    signed char* __restrict__ qV2,           // [CH][256][512] (d-major)
    float* __restrict__ norm2,               // [B][512]
    int b0) {
    __shared__ __align__(16) signed char As[16384];   // 128 rows x 128B
    __shared__ __align__(16) signed char Bs[16384];
    int m0 = blockIdx.x * 128;        // d
    int o0 = blockIdx.y * 128;        // o
    int bc = blockIdx.z;
    int b = b0 + bc;
    int tid = threadIdx.x;
    int l = tid & 63, w = tid >> 6;
    int quad = l >> 4, l16 = l & 15;
    int wm = (w >> 1) * 64, wn = (w & 1) * 64;
    const unsigned char* mrow = m1q + (size_t)b * D1;

    const signed char* pa[4];
    const signed char* pb[4];
    int lrow = l >> 3, ls = l & 7;
    #pragma unroll
    for (int r = 0; r < 4; r++) {
        int row = r * 32 + w * 8 + lrow;
        int c = (ls + (row & 7)) & 7;
        pa[r] = W1Ti8 + (size_t)(m0 + row) * D1 + c * 16;
        pb[r] = W2i8 + (size_t)(o0 + row) * D1 + c * 16;
    }
    int aoff[4][2], boff[4][2];
    #pragma unroll
    for (int mt = 0; mt < 4; mt++) {
        int tr = wm + mt * 16 + l16;
        #pragma unroll
        for (int ks = 0; ks < 2; ks++)
            aoff[mt][ks] = tr * 128 + (((ks * 4 + quad) - (tr & 7)) & 7) * 16;
    }
    #pragma unroll
    for (int nt = 0; nt < 4; nt++) {
        int tr = wn + nt * 16 + l16;
        #pragma unroll
        for (int ks = 0; ks < 2; ks++)
            boff[nt][ks] = tr * 128 + (((ks * 4 + quad) - (tr & 7)) & 7) * 16;
    }

    i32x4 acc[4][4];
    #pragma unroll
    for (int i = 0; i < 4; i++)
        #pragma unroll
        for (int j = 0; j < 4; j++) acc[i][j] = (i32x4)0;

    for (int kk = 0; kk < D1; kk += 128) {
        #pragma unroll
        for (int r = 0; r < 4; r++) {
            gld16(pa[r] + kk, As + r * 4096 + w * 1024);
            gld16(pb[r] + kk, Bs + r * 4096 + w * 1024);
        }
        i32x4 mv0 = *(const i32x4*)(mrow + kk + quad * 16);
        i32x4 mv1 = *(const i32x4*)(mrow + kk + 64 + quad * 16);
        __syncthreads();
        #pragma unroll
        for (int ks = 0; ks < 2; ks++) {
            i32x4 mv = ks ? mv1 : mv0;
            i32x4 a[4], bq[4];
            #pragma unroll
            for (int mt = 0; mt < 4; mt++)
                a[mt] = (*(const i32x4*)(As + aoff[mt][ks])) & mv;
            #pragma unroll
            for (int nt = 0; nt < 4; nt++)
                bq[nt] = *(const i32x4*)(Bs + boff[nt][ks]);
            #pragma unroll
            for (int mt = 0; mt < 4; mt++)
                #pragma unroll
                for (int nt = 0; nt < 4; nt++)
                    acc[mt][nt] = __builtin_amdgcn_mfma_i32_16x16x64_i8(
                        a[mt], bq[nt], acc[mt][nt], 0, 0, 0);
        }
        __syncthreads();
    }

    // scales: d per (mt,r) rows; o per (nt) cols
    float sad[4][4];
    #pragma unroll
    for (int mt = 0; mt < 4; mt++)
        #pragma unroll
        for (int r = 0; r < 4; r++)
            sad[mt][r] = saq[m0 + wm + mt * 16 + quad * 4 + r];
    float sbv[4], sbdq[4];
    #pragma unroll
    for (int nt = 0; nt < 4; nt++) {
        sbv[nt] = sbq[o0 + wn + nt * 16 + l16];
        sbdq[nt] = sbv[nt] * (1.0f / CQ);
    }

    // norm2[o] += sum_d V2^2 (R5's cheap reduce)
    #pragma unroll
    for (int nt = 0; nt < 4; nt++) {
        float s = 0.f;
        #pragma unroll
        for (int mt = 0; mt < 4; mt++)
            #pragma unroll
            for (int r = 0; r < 4; r++) {
                float v = (float)acc[mt][nt][r] * sad[mt][r] * sbv[nt];
                s += v * v;
            }
        s += __shfl_down(s, 32, 64);
        s += __shfl_down(s, 16, 64);
        if (l < 16)
            atomicAdd(&norm2[(size_t)b * D2 + o0 + wn + nt * 16 + l], s);
    }

    // qV2[d][o] int8 byte stores: q = round(acc*sb[o]/CQ)  (dequant: *sa[d]*CQ)
    signed char* qb = qV2 + (size_t)bc * (D * D2);
    #pragma unroll
    for (int mt = 0; mt < 4; mt++) {
        int dbase = m0 + wm + mt * 16 + quad * 4;
        #pragma unroll
        for (int r = 0; r < 4; r++)
            #pragma unroll
            for (int nt = 0; nt < 4; nt++) {
                int o = o0 + wn + nt * 16 + l16;
                int qi = __float2int_rn((float)acc[mt][nt][r] * sbdq[nt]);
                qi = max(-127, min(127, qi));
                qb[(size_t)(dbase + r) * D2 + o] = (signed char)qi;
            }
    }
}

// ---- GEMM2 (i8, BK=128): norm3[b][p] += s3[p]^2*sum_d (saCQ[d]*S3[p][d])^2 -
__global__ __launch_bounds__(256) void k_gemm2(
    const signed char* __restrict__ W3i8,    // [256][512]
    const signed char* __restrict__ qV2,     // [CH][256][512]
    const unsigned char* __restrict__ m2q,   // [B][512]
    const float* __restrict__ saq,           // [256]
    const float* __restrict__ s3q,           // [256]
    float* __restrict__ norm3,               // [B][256]
    int b0) {
    __shared__ __align__(16) signed char As[16384];
    __shared__ __align__(16) signed char Bs[16384];
    int m0 = blockIdx.x * 128;        // p
    int n0 = blockIdx.y * 128;        // d
    int bc = blockIdx.z;
    int b = b0 + bc;
    int tid = threadIdx.x;
    int l = tid & 63, w = tid >> 6;
    int quad = l >> 4, l16 = l & 15;
    int wm = (w >> 1) * 64, wn = (w & 1) * 64;
    const unsigned char* mrow = m2q + (size_t)b * D2;
    const signed char* Bsrc = qV2 + (size_t)bc * (D * D2);

    const signed char* pa[4];
    const signed char* pb[4];
    int lrow = l >> 3, ls = l & 7;
    #pragma unroll
    for (int r = 0; r < 4; r++) {
        int row = r * 32 + w * 8 + lrow;
        int c = (ls + (row & 7)) & 7;
        pa[r] = W3i8 + (size_t)(m0 + row) * D2 + c * 16;
        pb[r] = Bsrc + (size_t)(n0 + row) * D2 + c * 16;
    }
    int aoff[4][2], boff[4][2];
    #pragma unroll
    for (int mt = 0; mt < 4; mt++) {
        int tr = wm + mt * 16 + l16;
        #pragma unroll
        for (int ks = 0; ks < 2; ks++)
            aoff[mt][ks] = tr * 128 + (((ks * 4 + quad) - (tr & 7)) & 7) * 16;
    }
    #pragma unroll
    for (int nt = 0; nt < 4; nt++) {
        int tr = wn + nt * 16 + l16;
        #pragma unroll
        for (int ks = 0; ks < 2; ks++)
            boff[nt][ks] = tr * 128 + (((ks * 4 + quad) - (tr & 7)) & 7) * 16;
    }

    i32x4 acc[4][4];
    #pragma unroll
    for (int i = 0; i < 4; i++)
        #pragma unroll
        for (int j = 0; j < 4; j++) acc[i][j] = (i32x4)0;

    for (int kk = 0; kk < D2; kk += 128) {
        #pragma unroll
        for (int r = 0; r < 4; r++) {
            gld16(pa[r] + kk, As + r * 4096 + w * 1024);
            gld16(pb[r] + kk, Bs + r * 4096 + w * 1024);
        }
        i32x4 mv0 = *(const i32x4*)(mrow + kk + quad * 16);
        i32x4 mv1 = *(const i32x4*)(mrow + kk + 64 + quad * 16);
        __syncthreads();
        #pragma unroll
        for (int ks = 0; ks < 2; ks++) {
            i32x4 mv = ks ? mv1 : mv0;
            i32x4 a[4], bq[4];
            #pragma unroll
            for (int mt = 0; mt < 4; mt++)
                a[mt] = *(const i32x4*)(As + aoff[mt][ks]);
            #pragma unroll
            for (int nt = 0; nt < 4; nt++)
                bq[nt] = (*(const i32x4*)(Bs + boff[nt][ks])) & mv;
            #pragma unroll
            for (int mt = 0; mt < 4; mt++)
                #pragma unroll
                for (int nt = 0; nt < 4; nt++)
                    acc[mt][nt] = __builtin_amdgcn_mfma_i32_16x16x64_i8(
                        a[mt], bq[nt], acc[mt][nt], 0, 0, 0);
        }
        __syncthreads();
    }

    float saCQ[4];
    #pragma unroll
    for (int nt = 0; nt < 4; nt++)
        saCQ[nt] = saq[n0 + wn + nt * 16 + l16] * CQ;

    #pragma unroll
    for (int mt = 0; mt < 4; mt++)
        #pragma unroll
        for (int r = 0; r < 4; r++) {
            float s = 0.f;
            #pragma unroll
            for (int nt = 0; nt < 4; nt++) {
                float v = (float)acc[mt][nt][r] * saCQ[nt];
                s += v * v;
            }
            s += __shfl_down(s, 8, 64);
            s += __shfl_down(s, 4, 64);
            s += __shfl_down(s, 2, 64);
            s += __shfl_down(s, 1, 64);
            if (l16 == 0) {
                int p = m0 + wm + mt * 16 + quad * 4 + r;
                float s3 = s3q[p];
                atomicAdd(&norm3[(size_t)b * D3 + p], s * s3 * s3);
            }
        }
}

// ---- per-batch k-smallest sum; dist2/dist3 inline; atomic to out -----------
__global__ __launch_bounds__(256) void k_topk(
    const float* __restrict__ dists,    // [B][D1] dist1 only
    const float* __restrict__ z2, const float* __restrict__ norm2,
    const float* __restrict__ z3, const float* __restrict__ norm3,
    const int* __restrict__ kp, float* __restrict__ outp) {
    __shared__ unsigned long long wmin[4];
    int b = blockIdx.x, t = threadIdx.x;
    float lv[7];
    #pragma unroll
    for (int j = 0; j < 4; j++) lv[j] = dists[(size_t)b * D1 + t + 256 * j];
    #pragma unroll
    for (int j = 4; j < 6; j++) {
        int o = t + 256 * j - 1024;
        lv[j] = fabsf(z2[(size_t)b * D2 + o]) / sqrtf(norm2[(size_t)b * D2 + o]);
    }
    lv[6] = fabsf(z3[(size_t)b * D3 + t]) / sqrtf(norm3[(size_t)b * D3 + t]);
    int k = *kp;
    if (k > NDIST) k = NDIST;
    float sum = 0.f;
    for (int it = 0; it < k; it++) {
        float mv = lv[0]; int mj = 0;
        #pragma unroll
        for (int j = 1; j < 7; j++)
            if (lv[j] < mv) { mv = lv[j]; mj = j; }
        unsigned long long key =
            ((unsigned long long)__float_as_uint(mv) << 32) | (unsigned)(t * 8 + mj);
        #pragma unroll
        for (int off = 32; off > 0; off >>= 1) {
            unsigned long long o = __shfl_down(key, off, 64);
            if (o < key) key = o;
        }
        if ((t & 63) == 0) wmin[t >> 6] = key;
        __syncthreads();
        unsigned long long k0 = wmin[0];
        #pragma unroll
        for (int ww = 1; ww < 4; ww++) if (wmin[ww] < k0) k0 = wmin[ww];
        sum += __uint_as_float((unsigned)(k0 >> 32));
        int wt = (int)((k0 & 0xFFFu) >> 3), wj = (int)(k0 & 7u);
        if (t == wt) lv[wj] = FLT_MAX;
        __syncthreads();
    }
    if (t == 0) atomicAdd(outp, sum);
}

extern "C" void kernel_launch(void* const* d_in, const int* in_sizes, int n_in,
                              void* d_out, int out_size, void* d_ws, size_t ws_size,
                              hipStream_t stream) {
    const float* x  = (const float*)d_in[0];
    const float* W1 = (const float*)d_in[1];
    const float* b1 = (const float*)d_in[2];
    const float* W2 = (const float*)d_in[3];
    const float* b2 = (const float*)d_in[4];
    const float* W3 = (const float*)d_in[5];
    const float* b3 = (const float*)d_in[6];
    const int*   kp = (const int*)d_in[7];
    float* outp = (float*)d_out;

    float* fp = (float*)d_ws;
    float* rn1     = fp;                          fp += D1;
    float* dists   = fp;                          fp += (size_t)B * D1;
    float* saq     = fp;                          fp += D;
    float* sbq     = fp;                          fp += D2;
    float* s3q     = fp;                          fp += D3;
    // zero region: z2 || z3 || norm2 || norm3 (contiguous, 393216 floats)
    float* z2      = fp;                          fp += (size_t)B * D2;
    float* z3      = fp;                          fp += (size_t)B * D3;
    float* norm2   = fp;                          fp += (size_t)B * D2;
    float* norm3   = fp;                          fp += (size_t)B * D3;
    unsigned short* up = (unsigned short*)fp;
    unsigned short* W2hi  = up;  up += (size_t)D2 * D1;
    unsigned short* W2lo  = up;  up += (size_t)D2 * D1;
    unsigned short* W3hi  = up;  up += (size_t)D3 * D2;
    unsigned short* W3lo  = up;  up += (size_t)D3 * D2;
    unsigned short* xhi   = up;  up += (size_t)B * D;
    unsigned short* xlo   = up;  up += (size_t)B * D;
    unsigned short* W1hi  = up;  up += (size_t)D1 * D;
    unsigned short* W1lo  = up;  up += (size_t)D1 * D;
    unsigned short* h1hi  = up;  up += (size_t)B * D1;
    unsigned short* h1lo  = up;  up += (size_t)B * D1;
    unsigned short* h2hi  = up;  up += (size_t)B * D2;
    unsigned short* h2lo  = up;  up += (size_t)B * D2;
    signed char*    cp = (signed char*)up;
    signed char*    W1Ti8 = cp;  cp += (size_t)D * D1;
    signed char*    W2i8  = cp;  cp += (size_t)D2 * D1;
    signed char*    W3i8  = cp;  cp += (size_t)D3 * D2;
    unsigned char*  m1q   = (unsigned char*)cp;  cp += (size_t)B * D1;
    unsigned char*  m2q   = (unsigned char*)cp;  cp += (size_t)B * D2;
    signed char*    qV2   = cp;

    size_t base_bytes = (size_t)((char*)qV2 - (char*)d_ws);
    int CH = 8;
    const int cands[6] = {256, 128, 64, 32, 16, 8};
    for (int c = 0; c < 6; c++) {
        size_t need = base_bytes + (size_t)cands[c] * D * D2;
        if (need <= ws_size) { CH = cands[c]; break; }
    }

    k_prep<<<2976, 256, 0, stream>>>(x, W1, W2, W3, z2, outp,
                                     xhi, xlo, W1hi, W1lo, W2hi, W2lo, W3hi, W3lo,
                                     W1Ti8, saq, W2i8, sbq, W3i8, s3q, rn1);

    k_l1<<<dim3(B / 64, D1 / 64), 256, 0, stream>>>(xhi, xlo, W1hi, W1lo, b1, rn1,
                                                    dists, m1q, h1hi, h1lo);
    k_l2a<<<dim3(B / 64, D2 / 64, 4), 256, 0, stream>>>(h1hi, h1lo, W2hi, W2lo, z2);
    k_l2b<<<(B * D2) / 256, 256, 0, stream>>>(b2, z2, m2q, h2hi, h2lo);
    k_l3a<<<dim3(B / 64, D3 / 64, 2), 256, 0, stream>>>(h2hi, h2lo, W3hi, W3lo, z3);
    k_l3b<<<(B * D3) / 256, 256, 0, stream>>>(b3, z3);

    for (int b0 = 0; b0 < B; b0 += CH) {
        k_gemm1<<<dim3(D / 128, D2 / 128, CH), 256, 0, stream>>>(
            W1Ti8, W2i8, m1q, saq, sbq, qV2, norm2, b0);
        k_gemm2<<<dim3(D3 / 128, D / 128, CH), 256, 0, stream>>>(
            W3i8, qV2, m2q, saq, s3q, norm3, b0);
    }

    k_topk<<<B, 256, 0, stream>>>(dists, z2, norm2, z3, norm3, kp, outp);
}